// Round 4
// baseline (798.654 us; speedup 1.0000x reference)
//
#include <hip/hip_runtime.h>
#include <cstddef>
#include <cstdint>

#define N_USERS 100000
#define N_ITEMS 50000
#define N_NODES 150000
#define N_EDGES 3000000
// EMBED_DIM = 64 == wavefront size: lane d owns dim d of a row.

#define NBKT 293          // ceil(150000 / 512) buckets of 512 rows
#define BCHUNK 4096       // edges per multisplit block
#define ABLK ((N_EDGES + BCHUNK - 1) / BCHUNK)   // 733

typedef unsigned int uint32;
typedef unsigned short ushort16;

// fp32 -> bf16 with round-to-nearest-even
__device__ __forceinline__ ushort16 f2b(float f) {
    uint32 b = __float_as_uint(f);
    b += 0x7FFFu + ((b >> 16) & 1u);
    return (ushort16)(b >> 16);
}
__device__ __forceinline__ float b2f(ushort16 h) {
    return __uint_as_float(((uint32)h) << 16);
}

// ---------------- convert concat(user,item) -> bf16 allb ----------------
__global__ __launch_bounds__(256) void k_cvt(const float* __restrict__ user,
                                             const float* __restrict__ item,
                                             ushort16* __restrict__ allb) {
    int i = blockIdx.x * blockDim.x + threadIdx.x;          // float4 index
    const int total4 = N_NODES * 16;                        // 2,400,000
    if (i >= total4) return;
    const int user4 = N_USERS * 16;
    float4 v = (i < user4) ? ((const float4*)user)[i]
                           : ((const float4*)item)[i - user4];
    ushort4 h;
    h.x = f2b(v.x); h.y = f2b(v.y); h.z = f2b(v.z); h.w = f2b(v.w);
    ((ushort4*)allb)[i] = h;
}

// ---------------- phase A: bucket counts (LDS hist -> 293 global adds/block) ----
__global__ __launch_bounds__(256) void k_bucket_count(const int* __restrict__ rows,
                                                      int* __restrict__ bucket_cnt) {
    __shared__ int hist[NBKT];
    int t = threadIdx.x;
    for (int j = t; j < NBKT; j += 256) hist[j] = 0;
    __syncthreads();
    int s0 = blockIdx.x * BCHUNK;
    int e0 = min(s0 + BCHUNK, N_EDGES);
    for (int i = s0 + t; i < e0; i += 256)
        atomicAdd(&hist[rows[i] >> 9], 1);
    __syncthreads();
    for (int j = t; j < NBKT; j += 256)
        if (hist[j]) atomicAdd(&bucket_cnt[j], hist[j]);
}

// ---------------- tiny scan of 293 bucket counts ----------------
__global__ __launch_bounds__(512) void k_bucket_scan(const int* __restrict__ bucket_cnt,
                                                     int* __restrict__ bucket_start,
                                                     int* __restrict__ bucket_cursor,
                                                     int* __restrict__ row_start) {
    __shared__ int sh[512];
    int t = threadIdx.x;
    sh[t] = (t < NBKT) ? bucket_cnt[t] : 0;
    __syncthreads();
    for (int off = 1; off < 512; off <<= 1) {
        int add = (t >= off) ? sh[t - off] : 0;
        __syncthreads();
        sh[t] += add;
        __syncthreads();
    }
    if (t < NBKT) {
        int st = (t == 0) ? 0 : sh[t - 1];
        bucket_start[t] = st;
        bucket_cursor[t] = st;
    }
    if (t == 0) { bucket_start[NBKT] = N_EDGES; row_start[N_NODES] = N_EDGES; }
}

// ---------------- phase B: bucket scatter (block-local runs -> full lines) ------
// packs (col 18b | row_lo 9b << 18, val) into int2
__global__ __launch_bounds__(256) void k_bucket_scatter(const int* __restrict__ rows,
                                                        const int* __restrict__ cols,
                                                        const float* __restrict__ vals,
                                                        int* __restrict__ bucket_cursor,
                                                        int2* __restrict__ ebuf) {
    __shared__ int hist[NBKT];
    __shared__ int base[NBKT];
    int t = threadIdx.x;
    for (int j = t; j < NBKT; j += 256) hist[j] = 0;
    __syncthreads();
    int s0 = blockIdx.x * BCHUNK;
    int e0 = min(s0 + BCHUNK, N_EDGES);
    for (int i = s0 + t; i < e0; i += 256)
        atomicAdd(&hist[rows[i] >> 9], 1);
    __syncthreads();
    for (int j = t; j < NBKT; j += 256) {
        int c = hist[j];
        base[j] = c ? atomicAdd(&bucket_cursor[j], c) : 0;
    }
    for (int j = t; j < NBKT; j += 256) hist[j] = 0;
    __syncthreads();
    for (int i = s0 + t; i < e0; i += 256) {
        int r = rows[i];
        int b = r >> 9;
        int off = atomicAdd(&hist[b], 1);
        ebuf[base[b] + off] = make_int2(cols[i] | ((r & 511) << 18),
                                        __float_as_int(vals[i]));
    }
}

// ---------------- phase C: per-bucket sort to CSR + row_start emission ----------
__global__ __launch_bounds__(256) void k_sort_bucket(const int2* __restrict__ ebuf,
                                                     const int* __restrict__ bucket_start,
                                                     int* __restrict__ row_start,
                                                     int* __restrict__ cols_s,
                                                     float* __restrict__ vals_s) {
    __shared__ int rcnt[512];
    __shared__ int psum[256];
    __shared__ int curs[512];
    int b = blockIdx.x, t = threadIdx.x;
    int rbase = b << 9;
    rcnt[2 * t] = 0; rcnt[2 * t + 1] = 0;
    __syncthreads();
    int s = bucket_start[b], e = bucket_start[b + 1];
    for (int i = s + t; i < e; i += 256)
        atomicAdd(&rcnt[(ebuf[i].x >> 18) & 511], 1);
    __syncthreads();
    int a0 = rcnt[2 * t], a1 = rcnt[2 * t + 1];
    psum[t] = a0 + a1;
    __syncthreads();
    for (int off = 1; off < 256; off <<= 1) {
        int add = (t >= off) ? psum[t - off] : 0;
        __syncthreads();
        psum[t] += add;
        __syncthreads();
    }
    int ex = (t == 0) ? 0 : psum[t - 1];
    int r0 = s + ex;            // absolute CSR start of row rbase+2t
    int r1 = r0 + a0;
    curs[2 * t] = r0; curs[2 * t + 1] = r1;
    int rr = rbase + 2 * t;
    if (rr < N_NODES)     row_start[rr] = r0;
    if (rr + 1 < N_NODES) row_start[rr + 1] = r1;
    __syncthreads();
    for (int i = s + t; i < e; i += 256) {
        int2 ed = ebuf[i];
        int pos = atomicAdd(&curs[(ed.x >> 18) & 511], 1);
        cols_s[pos] = ed.x & 0x3FFFF;
        vals_s[pos] = __int_as_float(ed.y);
    }
}

// ---------------- per-row column sort (insertion, one thread per row) ----------
// Sorted columns synchronize all waves' passage through x -> L2-sized hot band.
__global__ __launch_bounds__(256) void k_rowsort(const int* __restrict__ row_start,
                                                 int* __restrict__ cols_s,
                                                 float* __restrict__ vals_s) {
    int r = blockIdx.x * blockDim.x + threadIdx.x;
    if (r >= N_NODES) return;
    int s = row_start[r], e = row_start[r + 1];
    for (int i = s + 1; i < e; ++i) {
        int   kc = cols_s[i];
        float kv = vals_s[i];
        int j = i - 1;
        while (j >= s && cols_s[j] > kc) {
            cols_s[j + 1] = cols_s[j];
            vals_s[j + 1] = vals_s[j];
            --j;
        }
        cols_s[j + 1] = kc;
        vals_s[j + 1] = kv;
    }
}

// ---------------- gather SpMM: one wave per row, lane = dim ----------------
// bf16 gather operand, fp32 math. LAYER 1: allb->y1b. LAYER 2: y1b->y2b.
// LAYER 3: y2b->out, fused epilogue out = 0.25*(e0 + y1 + y2 + acc).
template <int LAYER>
__global__ __launch_bounds__(256) void k_spmm(const int* __restrict__ row_start,
                                              const int* __restrict__ cols_s,
                                              const float* __restrict__ vals_s,
                                              const ushort16* __restrict__ x,
                                              ushort16* __restrict__ yb,
                                              const ushort16* __restrict__ y1b,
                                              const ushort16* __restrict__ y2b,
                                              const float* __restrict__ user,
                                              const float* __restrict__ item,
                                              float* __restrict__ out) {
    int gid = blockIdx.x * blockDim.x + threadIdx.x;
    int r = gid >> 6;
    int lane = threadIdx.x & 63;
    if (r >= N_NODES) return;
    int s = __builtin_amdgcn_readfirstlane(row_start[r]);
    int e = __builtin_amdgcn_readfirstlane(row_start[r + 1]);
    float acc = 0.f;
    int i = s;
    for (; i + 4 <= e; i += 4) {
        int   c0 = cols_s[i],   c1 = cols_s[i+1], c2 = cols_s[i+2], c3 = cols_s[i+3];
        float v0 = vals_s[i],   v1 = vals_s[i+1], v2 = vals_s[i+2], v3 = vals_s[i+3];
        float x0 = b2f(x[(size_t)c0 * 64 + lane]);
        float x1 = b2f(x[(size_t)c1 * 64 + lane]);
        float x2 = b2f(x[(size_t)c2 * 64 + lane]);
        float x3 = b2f(x[(size_t)c3 * 64 + lane]);
        acc += v0 * x0; acc += v1 * x1; acc += v2 * x2; acc += v3 * x3;
    }
    for (; i < e; ++i) acc += vals_s[i] * b2f(x[(size_t)cols_s[i] * 64 + lane]);

    size_t o = (size_t)r * 64 + lane;
    if constexpr (LAYER == 3) {
        float e0v = (r < N_USERS) ? user[o] : item[o - (size_t)N_USERS * 64];
        out[o] = 0.25f * (e0v + b2f(y1b[o]) + b2f(y2b[o]) + acc);
    } else {
        yb[o] = f2b(acc);
    }
}

// ---------------- fallback path (ws too small): atomic scatter SpMM ----------------
__global__ __launch_bounds__(256) void k_init(const float* __restrict__ user,
                                              const float* __restrict__ item,
                                              float* __restrict__ cur,
                                              float* __restrict__ out) {
    int i = blockIdx.x * blockDim.x + threadIdx.x;
    const int total4 = N_NODES * 16;
    if (i >= total4) return;
    const int user4 = N_USERS * 16;
    float4 v = (i < user4) ? ((const float4*)user)[i]
                           : ((const float4*)item)[i - user4];
    ((float4*)cur)[i] = v;
    ((float4*)out)[i] = make_float4(0.25f * v.x, 0.25f * v.y,
                                    0.25f * v.z, 0.25f * v.w);
}

__global__ __launch_bounds__(256) void k_edge_atomic(const int* __restrict__ rows,
                                                     const int* __restrict__ cols,
                                                     const float* __restrict__ vals,
                                                     const float* __restrict__ x,
                                                     float* __restrict__ y) {
    long long gid = (long long)blockIdx.x * blockDim.x + threadIdx.x;
    int e = (int)(gid >> 6);
    int lane = threadIdx.x & 63;
    if (e >= N_EDGES) return;
    int r = rows[e], c = cols[e];
    float v = vals[e];
    atomicAdd(&y[r * 64 + lane], v * x[c * 64 + lane]);
}

__global__ __launch_bounds__(256) void k_accum(const float* __restrict__ y,
                                               float* __restrict__ out) {
    int i = blockIdx.x * blockDim.x + threadIdx.x;
    const int total4 = N_NODES * 16;
    if (i >= total4) return;
    float4 a = ((const float4*)y)[i];
    float4 o = ((float4*)out)[i];
    o.x += 0.25f * a.x; o.y += 0.25f * a.y;
    o.z += 0.25f * a.z; o.w += 0.25f * a.w;
    ((float4*)out)[i] = o;
}

extern "C" void kernel_launch(void* const* d_in, const int* in_sizes, int n_in,
                              void* d_out, int out_size, void* d_ws, size_t ws_size,
                              hipStream_t stream) {
    const float* user = (const float*)d_in[0];
    const float* item = (const float*)d_in[1];
    const int*   rows = (const int*)d_in[2];
    const int*   cols = (const int*)d_in[3];
    const float* vals = (const float*)d_in[4];
    float* out = (float*)d_out;

    const int CVT_BLOCKS  = (N_NODES * 16 + 255) / 256;        // 9375
    const int SPMM_BLOCKS = (N_NODES * 64 + 255) / 256;        // 37500
    const int ROWSORT_BLOCKS = (N_NODES + 255) / 256;          // 586

    auto align256 = [](size_t x) { return (x + 255) & ~(size_t)255; };
    const size_t sz_embf = align256((size_t)N_NODES * 64 * sizeof(float));  // 38.4 MB
    const size_t sz_embb = align256((size_t)N_NODES * 64 * sizeof(short));  // 19.2 MB
    const size_t sz_edge = align256((size_t)N_EDGES * sizeof(int));         // 12 MB
    const size_t sz_rs   = align256((size_t)(N_NODES + 1) * sizeof(int));
    const size_t sz_bk   = align256((size_t)(NBKT + 1) * sizeof(int));
    const size_t need_csr = 3 * sz_embb + 2 * sz_edge + sz_rs + 3 * sz_bk;  // ~82.5 MB
    const size_t need_fb  = 2 * sz_embf;                                    // ~77 MB

    char* p = (char*)d_ws;
    if (ws_size >= need_csr) {
        ushort16* allb = (ushort16*)p; p += sz_embb;
        ushort16* y1b  = (ushort16*)p; p += sz_embb;   // ebuf (24 MB) aliases y1b+y2b
        ushort16* y2b  = (ushort16*)p; p += sz_embb;
        int*   cols_s    = (int*)p;   p += sz_edge;
        float* vals_s    = (float*)p; p += sz_edge;
        int*   row_start = (int*)p;   p += sz_rs;
        int*   bucket_cnt    = (int*)p; p += sz_bk;
        int*   bucket_start  = (int*)p; p += sz_bk;
        int*   bucket_cursor = (int*)p; p += sz_bk;
        int2*  ebuf = (int2*)y1b;      // dead before y1b is written

        hipMemsetAsync(bucket_cnt, 0, (size_t)NBKT * sizeof(int), stream);
        k_cvt<<<CVT_BLOCKS, 256, 0, stream>>>(user, item, allb);
        k_bucket_count<<<ABLK, 256, 0, stream>>>(rows, bucket_cnt);
        k_bucket_scan<<<1, 512, 0, stream>>>(bucket_cnt, bucket_start, bucket_cursor, row_start);
        k_bucket_scatter<<<ABLK, 256, 0, stream>>>(rows, cols, vals, bucket_cursor, ebuf);
        k_sort_bucket<<<NBKT, 256, 0, stream>>>(ebuf, bucket_start, row_start, cols_s, vals_s);
        k_rowsort<<<ROWSORT_BLOCKS, 256, 0, stream>>>(row_start, cols_s, vals_s);

        k_spmm<1><<<SPMM_BLOCKS, 256, 0, stream>>>(row_start, cols_s, vals_s, allb,
                                                   y1b, nullptr, nullptr, user, item, out);
        k_spmm<2><<<SPMM_BLOCKS, 256, 0, stream>>>(row_start, cols_s, vals_s, y1b,
                                                   y2b, nullptr, nullptr, user, item, out);
        k_spmm<3><<<SPMM_BLOCKS, 256, 0, stream>>>(row_start, cols_s, vals_s, y2b,
                                                   nullptr, y1b, y2b, user, item, out);
    } else {
        // fallback: atomic scatter SpMM (fp32), needs only 2 embedding buffers
        float* bufA = (float*)p; p += sz_embf;
        float* bufB = (float*)p; p += sz_embf;
        float* in   = bufA;
        float* y    = bufB;
        const long long EA_THREADS = (long long)N_EDGES * 64;
        const int EA_BLOCKS = (int)((EA_THREADS + 255) / 256);

        k_init<<<CVT_BLOCKS, 256, 0, stream>>>(user, item, in, out);
        for (int l = 0; l < 3; ++l) {
            hipMemsetAsync(y, 0, (size_t)N_NODES * 64 * sizeof(float), stream);
            k_edge_atomic<<<EA_BLOCKS, 256, 0, stream>>>(rows, cols, vals, in, y);
            k_accum<<<CVT_BLOCKS, 256, 0, stream>>>(y, out);
            float* t = in; in = y; y = t;
        }
    }
}

// Round 5
// 472.591 us; speedup vs baseline: 1.6899x; 1.6899x over previous
//
#include <hip/hip_runtime.h>
#include <cstddef>
#include <cstdint>

#define N_USERS 100000
#define N_ITEMS 50000
#define N_NODES 150000
#define N_EDGES 3000000
// EMBED_DIM = 64 == wavefront size: lane d owns dim d of a row.

#define NBKT 293          // ceil(150000 / 512) buckets of 512 rows
#define BCHUNK 4096       // edges per multisplit block
#define ABLK ((N_EDGES + BCHUNK - 1) / BCHUNK)   // 733

typedef unsigned int uint32;
typedef unsigned short ushort16;

// fp32 -> bf16 with round-to-nearest-even
__device__ __forceinline__ ushort16 f2b(float f) {
    uint32 b = __float_as_uint(f);
    b += 0x7FFFu + ((b >> 16) & 1u);
    return (ushort16)(b >> 16);
}
__device__ __forceinline__ float b2f(ushort16 h) {
    return __uint_as_float(((uint32)h) << 16);
}

// ---------------- convert concat(user,item) -> bf16 allb ----------------
__global__ __launch_bounds__(256) void k_cvt(const float* __restrict__ user,
                                             const float* __restrict__ item,
                                             ushort16* __restrict__ allb) {
    int i = blockIdx.x * blockDim.x + threadIdx.x;          // float4 index
    const int total4 = N_NODES * 16;                        // 2,400,000
    if (i >= total4) return;
    const int user4 = N_USERS * 16;
    float4 v = (i < user4) ? ((const float4*)user)[i]
                           : ((const float4*)item)[i - user4];
    ushort4 h;
    h.x = f2b(v.x); h.y = f2b(v.y); h.z = f2b(v.z); h.w = f2b(v.w);
    ((ushort4*)allb)[i] = h;
}

// ---------------- phase A: bucket counts (LDS hist -> 293 global adds/block) ----
__global__ __launch_bounds__(256) void k_bucket_count(const int* __restrict__ rows,
                                                      int* __restrict__ bucket_cnt) {
    __shared__ int hist[NBKT];
    int t = threadIdx.x;
    for (int j = t; j < NBKT; j += 256) hist[j] = 0;
    __syncthreads();
    int s0 = blockIdx.x * BCHUNK;
    int e0 = min(s0 + BCHUNK, N_EDGES);
    for (int i = s0 + t; i < e0; i += 256)
        atomicAdd(&hist[rows[i] >> 9], 1);
    __syncthreads();
    for (int j = t; j < NBKT; j += 256)
        if (hist[j]) atomicAdd(&bucket_cnt[j], hist[j]);
}

// ---------------- tiny scan of 293 bucket counts ----------------
__global__ __launch_bounds__(512) void k_bucket_scan(const int* __restrict__ bucket_cnt,
                                                     int* __restrict__ bucket_start,
                                                     int* __restrict__ bucket_cursor,
                                                     int* __restrict__ row_start) {
    __shared__ int sh[512];
    int t = threadIdx.x;
    sh[t] = (t < NBKT) ? bucket_cnt[t] : 0;
    __syncthreads();
    for (int off = 1; off < 512; off <<= 1) {
        int add = (t >= off) ? sh[t - off] : 0;
        __syncthreads();
        sh[t] += add;
        __syncthreads();
    }
    if (t < NBKT) {
        int st = (t == 0) ? 0 : sh[t - 1];
        bucket_start[t] = st;
        bucket_cursor[t] = st;
    }
    if (t == 0) { bucket_start[NBKT] = N_EDGES; row_start[N_NODES] = N_EDGES; }
}

// ---------------- phase B: bucket scatter (block-local runs -> full lines) ------
// packs (col 18b | row_lo 9b << 18, val) into int2
__global__ __launch_bounds__(256) void k_bucket_scatter(const int* __restrict__ rows,
                                                        const int* __restrict__ cols,
                                                        const float* __restrict__ vals,
                                                        int* __restrict__ bucket_cursor,
                                                        int2* __restrict__ ebuf) {
    __shared__ int hist[NBKT];
    __shared__ int base[NBKT];
    int t = threadIdx.x;
    for (int j = t; j < NBKT; j += 256) hist[j] = 0;
    __syncthreads();
    int s0 = blockIdx.x * BCHUNK;
    int e0 = min(s0 + BCHUNK, N_EDGES);
    for (int i = s0 + t; i < e0; i += 256)
        atomicAdd(&hist[rows[i] >> 9], 1);
    __syncthreads();
    for (int j = t; j < NBKT; j += 256) {
        int c = hist[j];
        base[j] = c ? atomicAdd(&bucket_cursor[j], c) : 0;
    }
    for (int j = t; j < NBKT; j += 256) hist[j] = 0;
    __syncthreads();
    for (int i = s0 + t; i < e0; i += 256) {
        int r = rows[i];
        int b = r >> 9;
        int off = atomicAdd(&hist[b], 1);
        ebuf[base[b] + off] = make_int2(cols[i] | ((r & 511) << 18),
                                        __float_as_int(vals[i]));
    }
}

// ---------------- phase C: per-bucket sort to CSR + row_start emission ----------
__global__ __launch_bounds__(256) void k_sort_bucket(const int2* __restrict__ ebuf,
                                                     const int* __restrict__ bucket_start,
                                                     int* __restrict__ row_start,
                                                     int* __restrict__ cols_s,
                                                     float* __restrict__ vals_s) {
    __shared__ int rcnt[512];
    __shared__ int psum[256];
    __shared__ int curs[512];
    int b = blockIdx.x, t = threadIdx.x;
    int rbase = b << 9;
    rcnt[2 * t] = 0; rcnt[2 * t + 1] = 0;
    __syncthreads();
    int s = bucket_start[b], e = bucket_start[b + 1];
    for (int i = s + t; i < e; i += 256)
        atomicAdd(&rcnt[(ebuf[i].x >> 18) & 511], 1);
    __syncthreads();
    int a0 = rcnt[2 * t], a1 = rcnt[2 * t + 1];
    psum[t] = a0 + a1;
    __syncthreads();
    for (int off = 1; off < 256; off <<= 1) {
        int add = (t >= off) ? psum[t - off] : 0;
        __syncthreads();
        psum[t] += add;
        __syncthreads();
    }
    int ex = (t == 0) ? 0 : psum[t - 1];
    int r0 = s + ex;            // absolute CSR start of row rbase+2t
    int r1 = r0 + a0;
    curs[2 * t] = r0; curs[2 * t + 1] = r1;
    int rr = rbase + 2 * t;
    if (rr < N_NODES)     row_start[rr] = r0;
    if (rr + 1 < N_NODES) row_start[rr + 1] = r1;
    __syncthreads();
    for (int i = s + t; i < e; i += 256) {
        int2 ed = ebuf[i];
        int pos = atomicAdd(&curs[(ed.x >> 18) & 511], 1);
        cols_s[pos] = ed.x & 0x3FFFF;
        vals_s[pos] = __int_as_float(ed.y);
    }
}

// ---------------- per-row column sort: one WAVE per row, bitonic in registers ---
// Sorted columns synchronize all waves' passage through x -> L2-sized hot band.
__global__ __launch_bounds__(256) void k_rowsort_wave(const int* __restrict__ row_start,
                                                      int* __restrict__ cols_s,
                                                      float* __restrict__ vals_s) {
    int gid = blockIdx.x * blockDim.x + threadIdx.x;
    int r = gid >> 6;
    int lane = threadIdx.x & 63;
    if (r >= N_NODES) return;
    int s = __builtin_amdgcn_readfirstlane(row_start[r]);
    int e = __builtin_amdgcn_readfirstlane(row_start[r + 1]);
    int d = e - s;
    if (d <= 1) return;
    if (d <= 64) {
        int   key = (lane < d) ? cols_s[s + lane] : 0x7FFFFFFF;
        float val = (lane < d) ? vals_s[s + lane] : 0.f;
        #pragma unroll
        for (int k = 2; k <= 64; k <<= 1) {
            #pragma unroll
            for (int j = k >> 1; j > 0; j >>= 1) {
                int   ok = __shfl_xor(key, j, 64);
                float ov = __shfl_xor(val, j, 64);
                bool lower = (lane & j) == 0;
                bool asc   = (lane & k) == 0;      // k=64: always ascending
                bool keepSmaller = (asc == lower);
                bool take = keepSmaller ? (ok < key) : (ok > key);
                if (take) { key = ok; val = ov; }
            }
        }
        if (lane < d) { cols_s[s + lane] = key; vals_s[s + lane] = val; }
    } else if (lane == 0) {
        // degenerate long row (statistically never): serial insertion
        for (int i = s + 1; i < e; ++i) {
            int kc = cols_s[i]; float kv = vals_s[i];
            int j = i - 1;
            while (j >= s && cols_s[j] > kc) {
                cols_s[j + 1] = cols_s[j]; vals_s[j + 1] = vals_s[j]; --j;
            }
            cols_s[j + 1] = kc; vals_s[j + 1] = kv;
        }
    }
}

// ---------------- gather SpMM: one wave per row, lane = dim ----------------
// bf16 gather operand, fp32 math. LAYER 1: allb->y1b. LAYER 2: y1b->y2b.
// LAYER 3: y2b->out, fused epilogue out = 0.25*(e0 + y1 + y2 + acc).
template <int LAYER>
__global__ __launch_bounds__(256) void k_spmm(const int* __restrict__ row_start,
                                              const int* __restrict__ cols_s,
                                              const float* __restrict__ vals_s,
                                              const ushort16* __restrict__ x,
                                              ushort16* __restrict__ yb,
                                              const ushort16* __restrict__ y1b,
                                              const ushort16* __restrict__ y2b,
                                              const float* __restrict__ user,
                                              const float* __restrict__ item,
                                              float* __restrict__ out) {
    int gid = blockIdx.x * blockDim.x + threadIdx.x;
    int r = gid >> 6;
    int lane = threadIdx.x & 63;
    if (r >= N_NODES) return;
    int s = __builtin_amdgcn_readfirstlane(row_start[r]);
    int e = __builtin_amdgcn_readfirstlane(row_start[r + 1]);
    float acc = 0.f;
    int i = s;
    for (; i + 4 <= e; i += 4) {
        int   c0 = cols_s[i],   c1 = cols_s[i+1], c2 = cols_s[i+2], c3 = cols_s[i+3];
        float v0 = vals_s[i],   v1 = vals_s[i+1], v2 = vals_s[i+2], v3 = vals_s[i+3];
        float x0 = b2f(x[(size_t)c0 * 64 + lane]);
        float x1 = b2f(x[(size_t)c1 * 64 + lane]);
        float x2 = b2f(x[(size_t)c2 * 64 + lane]);
        float x3 = b2f(x[(size_t)c3 * 64 + lane]);
        acc += v0 * x0; acc += v1 * x1; acc += v2 * x2; acc += v3 * x3;
    }
    for (; i < e; ++i) acc += vals_s[i] * b2f(x[(size_t)cols_s[i] * 64 + lane]);

    size_t o = (size_t)r * 64 + lane;
    if constexpr (LAYER == 3) {
        float e0v = (r < N_USERS) ? user[o] : item[o - (size_t)N_USERS * 64];
        out[o] = 0.25f * (e0v + b2f(y1b[o]) + b2f(y2b[o]) + acc);
    } else {
        yb[o] = f2b(acc);
    }
}

// ---------------- fallback path (ws too small): atomic scatter SpMM ----------------
__global__ __launch_bounds__(256) void k_init(const float* __restrict__ user,
                                              const float* __restrict__ item,
                                              float* __restrict__ cur,
                                              float* __restrict__ out) {
    int i = blockIdx.x * blockDim.x + threadIdx.x;
    const int total4 = N_NODES * 16;
    if (i >= total4) return;
    const int user4 = N_USERS * 16;
    float4 v = (i < user4) ? ((const float4*)user)[i]
                           : ((const float4*)item)[i - user4];
    ((float4*)cur)[i] = v;
    ((float4*)out)[i] = make_float4(0.25f * v.x, 0.25f * v.y,
                                    0.25f * v.z, 0.25f * v.w);
}

__global__ __launch_bounds__(256) void k_edge_atomic(const int* __restrict__ rows,
                                                     const int* __restrict__ cols,
                                                     const float* __restrict__ vals,
                                                     const float* __restrict__ x,
                                                     float* __restrict__ y) {
    long long gid = (long long)blockIdx.x * blockDim.x + threadIdx.x;
    int e = (int)(gid >> 6);
    int lane = threadIdx.x & 63;
    if (e >= N_EDGES) return;
    int r = rows[e], c = cols[e];
    float v = vals[e];
    atomicAdd(&y[r * 64 + lane], v * x[c * 64 + lane]);
}

__global__ __launch_bounds__(256) void k_accum(const float* __restrict__ y,
                                               float* __restrict__ out) {
    int i = blockIdx.x * blockDim.x + threadIdx.x;
    const int total4 = N_NODES * 16;
    if (i >= total4) return;
    float4 a = ((const float4*)y)[i];
    float4 o = ((float4*)out)[i];
    o.x += 0.25f * a.x; o.y += 0.25f * a.y;
    o.z += 0.25f * a.z; o.w += 0.25f * a.w;
    ((float4*)out)[i] = o;
}

extern "C" void kernel_launch(void* const* d_in, const int* in_sizes, int n_in,
                              void* d_out, int out_size, void* d_ws, size_t ws_size,
                              hipStream_t stream) {
    const float* user = (const float*)d_in[0];
    const float* item = (const float*)d_in[1];
    const int*   rows = (const int*)d_in[2];
    const int*   cols = (const int*)d_in[3];
    const float* vals = (const float*)d_in[4];
    float* out = (float*)d_out;

    const int CVT_BLOCKS  = (N_NODES * 16 + 255) / 256;        // 9375
    const int SPMM_BLOCKS = (N_NODES * 64 + 255) / 256;        // 37500

    auto align256 = [](size_t x) { return (x + 255) & ~(size_t)255; };
    const size_t sz_embf = align256((size_t)N_NODES * 64 * sizeof(float));  // 38.4 MB
    const size_t sz_embb = align256((size_t)N_NODES * 64 * sizeof(short));  // 19.2 MB
    const size_t sz_edge = align256((size_t)N_EDGES * sizeof(int));         // 12 MB
    const size_t sz_rs   = align256((size_t)(N_NODES + 1) * sizeof(int));
    const size_t sz_bk   = align256((size_t)(NBKT + 1) * sizeof(int));
    const size_t need_csr = 3 * sz_embb + 2 * sz_edge + sz_rs + 3 * sz_bk;  // ~82.5 MB

    char* p = (char*)d_ws;
    if (ws_size >= need_csr) {
        ushort16* allb = (ushort16*)p; p += sz_embb;
        ushort16* y1b  = (ushort16*)p; p += sz_embb;   // ebuf (24 MB) aliases y1b+y2b
        ushort16* y2b  = (ushort16*)p; p += sz_embb;
        int*   cols_s    = (int*)p;   p += sz_edge;
        float* vals_s    = (float*)p; p += sz_edge;
        int*   row_start = (int*)p;   p += sz_rs;
        int*   bucket_cnt    = (int*)p; p += sz_bk;
        int*   bucket_start  = (int*)p; p += sz_bk;
        int*   bucket_cursor = (int*)p; p += sz_bk;
        int2*  ebuf = (int2*)y1b;      // dead before y1b is written

        hipMemsetAsync(bucket_cnt, 0, (size_t)NBKT * sizeof(int), stream);
        k_cvt<<<CVT_BLOCKS, 256, 0, stream>>>(user, item, allb);
        k_bucket_count<<<ABLK, 256, 0, stream>>>(rows, bucket_cnt);
        k_bucket_scan<<<1, 512, 0, stream>>>(bucket_cnt, bucket_start, bucket_cursor, row_start);
        k_bucket_scatter<<<ABLK, 256, 0, stream>>>(rows, cols, vals, bucket_cursor, ebuf);
        k_sort_bucket<<<NBKT, 256, 0, stream>>>(ebuf, bucket_start, row_start, cols_s, vals_s);
        k_rowsort_wave<<<SPMM_BLOCKS, 256, 0, stream>>>(row_start, cols_s, vals_s);

        k_spmm<1><<<SPMM_BLOCKS, 256, 0, stream>>>(row_start, cols_s, vals_s, allb,
                                                   y1b, nullptr, nullptr, user, item, out);
        k_spmm<2><<<SPMM_BLOCKS, 256, 0, stream>>>(row_start, cols_s, vals_s, y1b,
                                                   y2b, nullptr, nullptr, user, item, out);
        k_spmm<3><<<SPMM_BLOCKS, 256, 0, stream>>>(row_start, cols_s, vals_s, y2b,
                                                   nullptr, y1b, y2b, user, item, out);
    } else {
        // fallback: atomic scatter SpMM (fp32), needs only 2 embedding buffers
        float* bufA = (float*)p; p += sz_embf;
        float* bufB = (float*)p; p += sz_embf;
        float* in   = bufA;
        float* y    = bufB;
        const long long EA_THREADS = (long long)N_EDGES * 64;
        const int EA_BLOCKS = (int)((EA_THREADS + 255) / 256);

        k_init<<<CVT_BLOCKS, 256, 0, stream>>>(user, item, in, out);
        for (int l = 0; l < 3; ++l) {
            hipMemsetAsync(y, 0, (size_t)N_NODES * 64 * sizeof(float), stream);
            k_edge_atomic<<<EA_BLOCKS, 256, 0, stream>>>(rows, cols, vals, in, y);
            k_accum<<<CVT_BLOCKS, 256, 0, stream>>>(y, out);
            float* t = in; in = y; y = t;
        }
    }
}

// Round 6
// 436.592 us; speedup vs baseline: 1.8293x; 1.0825x over previous
//
#include <hip/hip_runtime.h>
#include <cstddef>
#include <cstdint>

#define N_USERS 100000
#define N_ITEMS 50000
#define N_NODES 150000
#define N_EDGES 3000000
// EMBED_DIM = 64 == wavefront size: lane d owns dim d of a row.

#define NBKT 586          // ceil(150000 / 256) buckets of 256 rows
#define BCHUNK 4096       // edges per multisplit block
#define ABLK ((N_EDGES + BCHUNK - 1) / BCHUNK)   // 733
#define MAXE 6912         // LDS staging cap per bucket (avg 5120, std 72)

typedef unsigned int uint32;
typedef unsigned short ushort16;

// fp32 -> bf16 with round-to-nearest-even
__device__ __forceinline__ ushort16 f2b(float f) {
    uint32 b = __float_as_uint(f);
    b += 0x7FFFu + ((b >> 16) & 1u);
    return (ushort16)(b >> 16);
}
__device__ __forceinline__ float b2f(ushort16 h) {
    return __uint_as_float(((uint32)h) << 16);
}

// ---------------- convert concat(user,item) -> bf16 allb ----------------
__global__ __launch_bounds__(256) void k_cvt(const float* __restrict__ user,
                                             const float* __restrict__ item,
                                             ushort16* __restrict__ allb) {
    int i = blockIdx.x * blockDim.x + threadIdx.x;          // float4 index
    const int total4 = N_NODES * 16;                        // 2,400,000
    if (i >= total4) return;
    const int user4 = N_USERS * 16;
    float4 v = (i < user4) ? ((const float4*)user)[i]
                           : ((const float4*)item)[i - user4];
    ushort4 h;
    h.x = f2b(v.x); h.y = f2b(v.y); h.z = f2b(v.z); h.w = f2b(v.w);
    ((ushort4*)allb)[i] = h;
}

// ---------------- phase A: bucket counts (LDS hist -> 586 global adds/block) ----
__global__ __launch_bounds__(256) void k_bucket_count(const int* __restrict__ rows,
                                                      int* __restrict__ bucket_cnt) {
    __shared__ int hist[NBKT];
    int t = threadIdx.x;
    for (int j = t; j < NBKT; j += 256) hist[j] = 0;
    __syncthreads();
    int s0 = blockIdx.x * BCHUNK;
    int e0 = min(s0 + BCHUNK, N_EDGES);
    for (int i = s0 + t; i < e0; i += 256)
        atomicAdd(&hist[rows[i] >> 8], 1);
    __syncthreads();
    for (int j = t; j < NBKT; j += 256)
        if (hist[j]) atomicAdd(&bucket_cnt[j], hist[j]);
}

// ---------------- tiny scan of 586 bucket counts ----------------
__global__ __launch_bounds__(1024) void k_bucket_scan(const int* __restrict__ bucket_cnt,
                                                      int* __restrict__ bucket_start,
                                                      int* __restrict__ bucket_cursor,
                                                      int* __restrict__ row_start) {
    __shared__ int sh[1024];
    int t = threadIdx.x;
    sh[t] = (t < NBKT) ? bucket_cnt[t] : 0;
    __syncthreads();
    for (int off = 1; off < 1024; off <<= 1) {
        int add = (t >= off) ? sh[t - off] : 0;
        __syncthreads();
        sh[t] += add;
        __syncthreads();
    }
    if (t < NBKT) {
        int st = (t == 0) ? 0 : sh[t - 1];
        bucket_start[t] = st;
        bucket_cursor[t] = st;
    }
    if (t == 0) { bucket_start[NBKT] = N_EDGES; row_start[N_NODES] = N_EDGES; }
}

// ---------------- phase B: bucket scatter (block-local runs -> full lines) ------
// packs (col 18b | row_lo 8b << 18, val) into int2
__global__ __launch_bounds__(256) void k_bucket_scatter(const int* __restrict__ rows,
                                                        const int* __restrict__ cols,
                                                        const float* __restrict__ vals,
                                                        int* __restrict__ bucket_cursor,
                                                        int2* __restrict__ ebuf) {
    __shared__ int hist[NBKT];
    __shared__ int base[NBKT];
    int t = threadIdx.x;
    for (int j = t; j < NBKT; j += 256) hist[j] = 0;
    __syncthreads();
    int s0 = blockIdx.x * BCHUNK;
    int e0 = min(s0 + BCHUNK, N_EDGES);
    for (int i = s0 + t; i < e0; i += 256)
        atomicAdd(&hist[rows[i] >> 8], 1);
    __syncthreads();
    for (int j = t; j < NBKT; j += 256) {
        int c = hist[j];
        base[j] = c ? atomicAdd(&bucket_cursor[j], c) : 0;
    }
    for (int j = t; j < NBKT; j += 256) hist[j] = 0;
    __syncthreads();
    for (int i = s0 + t; i < e0; i += 256) {
        int r = rows[i];
        int b = r >> 8;
        int off = atomicAdd(&hist[b], 1);
        ebuf[base[b] + off] = make_int2(cols[i] | ((r & 255) << 18),
                                        __float_as_int(vals[i]));
    }
}

// ---------------- phase C: per-bucket CSR + in-LDS per-row column sort ----------
// Scatter bucket edges into LDS at CSR positions, insertion-sort each row by col
// (one thread per row), then write packed (col,val) out coalesced.
__global__ __launch_bounds__(256) void k_sort_bucket(const int2* __restrict__ ebuf,
                                                     const int* __restrict__ bucket_start,
                                                     int* __restrict__ row_start,
                                                     int2* __restrict__ ecsr) {
    __shared__ int  rcnt[256];
    __shared__ int  psum[256];
    __shared__ int  curs[256];
    __shared__ int2 dst[MAXE];
    int b = blockIdx.x, t = threadIdx.x;
    int rbase = b << 8;
    rcnt[t] = 0;
    __syncthreads();
    int s = bucket_start[b], e = bucket_start[b + 1];
    int n = e - s;
    for (int i = s + t; i < e; i += 256)
        atomicAdd(&rcnt[(ebuf[i].x >> 18) & 255], 1);
    __syncthreads();
    int cnt = rcnt[t];
    psum[t] = cnt;
    __syncthreads();
    for (int off = 1; off < 256; off <<= 1) {
        int add = (t >= off) ? psum[t - off] : 0;
        __syncthreads();
        psum[t] += add;
        __syncthreads();
    }
    int ex = psum[t] - cnt;            // relative CSR start of row rbase+t
    curs[t] = ex;
    int rr = rbase + t;
    if (rr < N_NODES) row_start[rr] = s + ex;
    __syncthreads();
    if (n <= MAXE) {
        for (int i = s + t; i < e; i += 256) {
            int2 ed = ebuf[i];
            int pos = atomicAdd(&curs[(ed.x >> 18) & 255], 1);
            dst[pos] = make_int2(ed.x & 0x3FFFF, ed.y);
        }
        __syncthreads();
        // insertion-sort row t's segment [ex, ex+cnt) by col
        for (int i = ex + 1; i < ex + cnt; ++i) {
            int2 k = dst[i];
            int j = i - 1;
            while (j >= ex && dst[j].x > k.x) { dst[j + 1] = dst[j]; --j; }
            dst[j + 1] = k;
        }
        __syncthreads();
        for (int i = t; i < n; i += 256) ecsr[s + i] = dst[i];
    } else {
        // degenerate oversized bucket (statistically never): unsorted direct
        for (int i = s + t; i < e; i += 256) {
            int2 ed = ebuf[i];
            int pos = atomicAdd(&curs[(ed.x >> 18) & 255], 1);
            ecsr[s + pos] = make_int2(ed.x & 0x3FFFF, ed.y);
        }
    }
}

// ---------------- gather SpMM: one wave per row, lane = dim ----------------
// bf16 gather operand, fp32 math, packed int2 edges. LAYER 1: allb->y1b.
// LAYER 2: y1b->y2b. LAYER 3: y2b->out, fused out = 0.25*(e0+y1+y2+acc).
template <int LAYER>
__global__ __launch_bounds__(256) void k_spmm(const int* __restrict__ row_start,
                                              const int2* __restrict__ ecsr,
                                              const ushort16* __restrict__ x,
                                              ushort16* __restrict__ yb,
                                              const ushort16* __restrict__ y1b,
                                              const ushort16* __restrict__ y2b,
                                              const float* __restrict__ user,
                                              const float* __restrict__ item,
                                              float* __restrict__ out) {
    int gid = blockIdx.x * blockDim.x + threadIdx.x;
    int r = gid >> 6;
    int lane = threadIdx.x & 63;
    if (r >= N_NODES) return;
    int s = __builtin_amdgcn_readfirstlane(row_start[r]);
    int e = __builtin_amdgcn_readfirstlane(row_start[r + 1]);
    float acc = 0.f;
    int i = s;
    for (; i + 8 <= e; i += 8) {
        int2 e0 = ecsr[i],   e1 = ecsr[i+1], e2 = ecsr[i+2], e3 = ecsr[i+3];
        int2 e4 = ecsr[i+4], e5 = ecsr[i+5], e6 = ecsr[i+6], e7 = ecsr[i+7];
        float x0 = b2f(x[(size_t)e0.x * 64 + lane]);
        float x1 = b2f(x[(size_t)e1.x * 64 + lane]);
        float x2 = b2f(x[(size_t)e2.x * 64 + lane]);
        float x3 = b2f(x[(size_t)e3.x * 64 + lane]);
        float x4 = b2f(x[(size_t)e4.x * 64 + lane]);
        float x5 = b2f(x[(size_t)e5.x * 64 + lane]);
        float x6 = b2f(x[(size_t)e6.x * 64 + lane]);
        float x7 = b2f(x[(size_t)e7.x * 64 + lane]);
        acc += __int_as_float(e0.y) * x0; acc += __int_as_float(e1.y) * x1;
        acc += __int_as_float(e2.y) * x2; acc += __int_as_float(e3.y) * x3;
        acc += __int_as_float(e4.y) * x4; acc += __int_as_float(e5.y) * x5;
        acc += __int_as_float(e6.y) * x6; acc += __int_as_float(e7.y) * x7;
    }
    for (; i + 4 <= e; i += 4) {
        int2 e0 = ecsr[i], e1 = ecsr[i+1], e2 = ecsr[i+2], e3 = ecsr[i+3];
        float x0 = b2f(x[(size_t)e0.x * 64 + lane]);
        float x1 = b2f(x[(size_t)e1.x * 64 + lane]);
        float x2 = b2f(x[(size_t)e2.x * 64 + lane]);
        float x3 = b2f(x[(size_t)e3.x * 64 + lane]);
        acc += __int_as_float(e0.y) * x0; acc += __int_as_float(e1.y) * x1;
        acc += __int_as_float(e2.y) * x2; acc += __int_as_float(e3.y) * x3;
    }
    for (; i < e; ++i) {
        int2 ed = ecsr[i];
        acc += __int_as_float(ed.y) * b2f(x[(size_t)ed.x * 64 + lane]);
    }

    size_t o = (size_t)r * 64 + lane;
    if constexpr (LAYER == 3) {
        float e0v = (r < N_USERS) ? user[o] : item[o - (size_t)N_USERS * 64];
        out[o] = 0.25f * (e0v + b2f(y1b[o]) + b2f(y2b[o]) + acc);
    } else {
        yb[o] = f2b(acc);
    }
}

// ---------------- fallback path (ws too small): atomic scatter SpMM ----------------
__global__ __launch_bounds__(256) void k_init(const float* __restrict__ user,
                                              const float* __restrict__ item,
                                              float* __restrict__ cur,
                                              float* __restrict__ out) {
    int i = blockIdx.x * blockDim.x + threadIdx.x;
    const int total4 = N_NODES * 16;
    if (i >= total4) return;
    const int user4 = N_USERS * 16;
    float4 v = (i < user4) ? ((const float4*)user)[i]
                           : ((const float4*)item)[i - user4];
    ((float4*)cur)[i] = v;
    ((float4*)out)[i] = make_float4(0.25f * v.x, 0.25f * v.y,
                                    0.25f * v.z, 0.25f * v.w);
}

__global__ __launch_bounds__(256) void k_edge_atomic(const int* __restrict__ rows,
                                                     const int* __restrict__ cols,
                                                     const float* __restrict__ vals,
                                                     const float* __restrict__ x,
                                                     float* __restrict__ y) {
    long long gid = (long long)blockIdx.x * blockDim.x + threadIdx.x;
    int e = (int)(gid >> 6);
    int lane = threadIdx.x & 63;
    if (e >= N_EDGES) return;
    int r = rows[e], c = cols[e];
    float v = vals[e];
    atomicAdd(&y[r * 64 + lane], v * x[c * 64 + lane]);
}

__global__ __launch_bounds__(256) void k_accum(const float* __restrict__ y,
                                               float* __restrict__ out) {
    int i = blockIdx.x * blockDim.x + threadIdx.x;
    const int total4 = N_NODES * 16;
    if (i >= total4) return;
    float4 a = ((const float4*)y)[i];
    float4 o = ((float4*)out)[i];
    o.x += 0.25f * a.x; o.y += 0.25f * a.y;
    o.z += 0.25f * a.z; o.w += 0.25f * a.w;
    ((float4*)out)[i] = o;
}

extern "C" void kernel_launch(void* const* d_in, const int* in_sizes, int n_in,
                              void* d_out, int out_size, void* d_ws, size_t ws_size,
                              hipStream_t stream) {
    const float* user = (const float*)d_in[0];
    const float* item = (const float*)d_in[1];
    const int*   rows = (const int*)d_in[2];
    const int*   cols = (const int*)d_in[3];
    const float* vals = (const float*)d_in[4];
    float* out = (float*)d_out;

    const int CVT_BLOCKS  = (N_NODES * 16 + 255) / 256;        // 9375
    const int SPMM_BLOCKS = (N_NODES * 64 + 255) / 256;        // 37500

    auto align256 = [](size_t x) { return (x + 255) & ~(size_t)255; };
    const size_t sz_embf = align256((size_t)N_NODES * 64 * sizeof(float));  // 38.4 MB
    const size_t sz_embb = align256((size_t)N_NODES * 64 * sizeof(short));  // 19.2 MB
    const size_t sz_ecsr = align256((size_t)N_EDGES * sizeof(int2));        // 24 MB
    const size_t sz_rs   = align256((size_t)(N_NODES + 1) * sizeof(int));
    const size_t sz_bk   = align256((size_t)(NBKT + 1) * sizeof(int));
    const size_t need_csr = 3 * sz_embb + sz_ecsr + sz_rs + 3 * sz_bk;      // ~82.5 MB

    char* p = (char*)d_ws;
    if (ws_size >= need_csr) {
        ushort16* allb = (ushort16*)p; p += sz_embb;
        ushort16* y1b  = (ushort16*)p; p += sz_embb;   // ebuf (24 MB) aliases y1b+y2b
        ushort16* y2b  = (ushort16*)p; p += sz_embb;
        int2*  ecsr      = (int2*)p;  p += sz_ecsr;
        int*   row_start = (int*)p;   p += sz_rs;
        int*   bucket_cnt    = (int*)p; p += sz_bk;
        int*   bucket_start  = (int*)p; p += sz_bk;
        int*   bucket_cursor = (int*)p; p += sz_bk;
        int2*  ebuf = (int2*)y1b;      // dead before y1b is written

        hipMemsetAsync(bucket_cnt, 0, (size_t)NBKT * sizeof(int), stream);
        k_cvt<<<CVT_BLOCKS, 256, 0, stream>>>(user, item, allb);
        k_bucket_count<<<ABLK, 256, 0, stream>>>(rows, bucket_cnt);
        k_bucket_scan<<<1, 1024, 0, stream>>>(bucket_cnt, bucket_start, bucket_cursor, row_start);
        k_bucket_scatter<<<ABLK, 256, 0, stream>>>(rows, cols, vals, bucket_cursor, ebuf);
        k_sort_bucket<<<NBKT, 256, 0, stream>>>(ebuf, bucket_start, row_start, ecsr);

        k_spmm<1><<<SPMM_BLOCKS, 256, 0, stream>>>(row_start, ecsr, allb,
                                                   y1b, nullptr, nullptr, user, item, out);
        k_spmm<2><<<SPMM_BLOCKS, 256, 0, stream>>>(row_start, ecsr, y1b,
                                                   y2b, nullptr, nullptr, user, item, out);
        k_spmm<3><<<SPMM_BLOCKS, 256, 0, stream>>>(row_start, ecsr, y2b,
                                                   nullptr, y1b, y2b, user, item, out);
    } else {
        // fallback: atomic scatter SpMM (fp32), needs only 2 embedding buffers
        float* bufA = (float*)p; p += sz_embf;
        float* bufB = (float*)p; p += sz_embf;
        float* in   = bufA;
        float* y    = bufB;
        const long long EA_THREADS = (long long)N_EDGES * 64;
        const int EA_BLOCKS = (int)((EA_THREADS + 255) / 256);

        k_init<<<CVT_BLOCKS, 256, 0, stream>>>(user, item, in, out);
        for (int l = 0; l < 3; ++l) {
            hipMemsetAsync(y, 0, (size_t)N_NODES * 64 * sizeof(float), stream);
            k_edge_atomic<<<EA_BLOCKS, 256, 0, stream>>>(rows, cols, vals, in, y);
            k_accum<<<CVT_BLOCKS, 256, 0, stream>>>(y, out);
            float* t = in; in = y; y = t;
        }
    }
}

// Round 7
// 433.329 us; speedup vs baseline: 1.8431x; 1.0075x over previous
//
#include <hip/hip_runtime.h>
#include <cstddef>
#include <cstdint>

#define N_USERS 100000
#define N_ITEMS 50000
#define N_NODES 150000
#define N_EDGES 3000000
// EMBED_DIM = 64 == wavefront size: lane d owns dim d of a row.

#define NBKT 586          // ceil(150000 / 256) buckets of 256 rows
#define BCHUNK 4096       // edges per multisplit block
#define ABLK ((N_EDGES + BCHUNK - 1) / BCHUNK)   // 733
#define MAXE 6016         // LDS staging cap per bucket (avg 5120, sigma 72 -> +12.5s)

typedef unsigned int uint32;
typedef unsigned short ushort16;

// fp32 -> bf16 with round-to-nearest-even
__device__ __forceinline__ ushort16 f2b(float f) {
    uint32 b = __float_as_uint(f);
    b += 0x7FFFu + ((b >> 16) & 1u);
    return (ushort16)(b >> 16);
}
__device__ __forceinline__ float b2f(ushort16 h) {
    return __uint_as_float(((uint32)h) << 16);
}

// ---------------- convert concat(user,item) -> bf16 allb ----------------
__global__ __launch_bounds__(256) void k_cvt(const float* __restrict__ user,
                                             const float* __restrict__ item,
                                             ushort16* __restrict__ allb) {
    int i = blockIdx.x * blockDim.x + threadIdx.x;          // float4 index
    const int total4 = N_NODES * 16;                        // 2,400,000
    if (i >= total4) return;
    const int user4 = N_USERS * 16;
    float4 v = (i < user4) ? ((const float4*)user)[i]
                           : ((const float4*)item)[i - user4];
    ushort4 h;
    h.x = f2b(v.x); h.y = f2b(v.y); h.z = f2b(v.z); h.w = f2b(v.w);
    ((ushort4*)allb)[i] = h;
}

// ---------------- phase A: bucket counts (LDS hist -> 586 global adds/block) ----
__global__ __launch_bounds__(256) void k_bucket_count(const int* __restrict__ rows,
                                                      int* __restrict__ bucket_cnt) {
    __shared__ int hist[NBKT];
    int t = threadIdx.x;
    for (int j = t; j < NBKT; j += 256) hist[j] = 0;
    __syncthreads();
    int s0 = blockIdx.x * BCHUNK;
    int e0 = min(s0 + BCHUNK, N_EDGES);
    for (int i = s0 + t; i < e0; i += 256)
        atomicAdd(&hist[rows[i] >> 8], 1);
    __syncthreads();
    for (int j = t; j < NBKT; j += 256)
        if (hist[j]) atomicAdd(&bucket_cnt[j], hist[j]);
}

// ---------------- tiny scan of 586 bucket counts ----------------
__global__ __launch_bounds__(1024) void k_bucket_scan(const int* __restrict__ bucket_cnt,
                                                      int* __restrict__ bucket_start,
                                                      int* __restrict__ bucket_cursor,
                                                      int* __restrict__ row_start) {
    __shared__ int sh[1024];
    int t = threadIdx.x;
    sh[t] = (t < NBKT) ? bucket_cnt[t] : 0;
    __syncthreads();
    for (int off = 1; off < 1024; off <<= 1) {
        int add = (t >= off) ? sh[t - off] : 0;
        __syncthreads();
        sh[t] += add;
        __syncthreads();
    }
    if (t < NBKT) {
        int st = (t == 0) ? 0 : sh[t - 1];
        bucket_start[t] = st;
        bucket_cursor[t] = st;
    }
    if (t == 0) { bucket_start[NBKT] = N_EDGES; row_start[N_NODES] = N_EDGES; }
}

// ---------------- phase B: bucket scatter (block-local runs -> full lines) ------
// packs (col 18b | row_lo 8b << 18, val) into int2
__global__ __launch_bounds__(256) void k_bucket_scatter(const int* __restrict__ rows,
                                                        const int* __restrict__ cols,
                                                        const float* __restrict__ vals,
                                                        int* __restrict__ bucket_cursor,
                                                        int2* __restrict__ ebuf) {
    __shared__ int hist[NBKT];
    __shared__ int base[NBKT];
    int t = threadIdx.x;
    for (int j = t; j < NBKT; j += 256) hist[j] = 0;
    __syncthreads();
    int s0 = blockIdx.x * BCHUNK;
    int e0 = min(s0 + BCHUNK, N_EDGES);
    for (int i = s0 + t; i < e0; i += 256)
        atomicAdd(&hist[rows[i] >> 8], 1);
    __syncthreads();
    for (int j = t; j < NBKT; j += 256) {
        int c = hist[j];
        base[j] = c ? atomicAdd(&bucket_cursor[j], c) : 0;
    }
    for (int j = t; j < NBKT; j += 256) hist[j] = 0;
    __syncthreads();
    for (int i = s0 + t; i < e0; i += 256) {
        int r = rows[i];
        int b = r >> 8;
        int off = atomicAdd(&hist[b], 1);
        ebuf[base[b] + off] = make_int2(cols[i] | ((r & 255) << 18),
                                        __float_as_int(vals[i]));
    }
}

// ---------------- phase C: per-bucket CSR + per-row register-bitonic sort -------
// Scatter bucket edges into LDS at CSR positions; each wave then sorts 64
// consecutive rows (<=64 edges each) with a shfl_xor bitonic in REGISTERS
// (no LDS traffic, no bank conflicts) and writes sorted (col,val) straight
// to global ecsr, coalesced per wave span.
__global__ __launch_bounds__(256) void k_sort_bucket(const int2* __restrict__ ebuf,
                                                     const int* __restrict__ bucket_start,
                                                     int* __restrict__ row_start,
                                                     int2* __restrict__ ecsr) {
    __shared__ int  rcnt[256];
    __shared__ int  psum[256];
    __shared__ int  rex[256];
    __shared__ int  curs[256];
    __shared__ int2 dst[MAXE];
    int b = blockIdx.x, t = threadIdx.x;
    int rbase = b << 8;
    rcnt[t] = 0;
    __syncthreads();
    int s = bucket_start[b], e = bucket_start[b + 1];
    int n = e - s;
    for (int i = s + t; i < e; i += 256)
        atomicAdd(&rcnt[(ebuf[i].x >> 18) & 255], 1);
    __syncthreads();
    int cnt = rcnt[t];
    psum[t] = cnt;
    __syncthreads();
    for (int off = 1; off < 256; off <<= 1) {
        int add = (t >= off) ? psum[t - off] : 0;
        __syncthreads();
        psum[t] += add;
        __syncthreads();
    }
    int ex = psum[t] - cnt;            // relative CSR start of row rbase+t
    rex[t] = ex;
    curs[t] = ex;
    int rr = rbase + t;
    if (rr < N_NODES) row_start[rr] = s + ex;
    __syncthreads();
    if (n <= MAXE) {
        for (int i = s + t; i < e; i += 256) {
            int2 ed = ebuf[i];
            int pos = atomicAdd(&curs[(ed.x >> 18) & 255], 1);
            dst[pos] = make_int2(ed.x & 0x3FFFF, ed.y);
        }
        __syncthreads();
        // wave w sorts rows [w*64, w*64+64) -- row index uniform across wave
        int wid = t >> 6, lane = t & 63;
        for (int rw = 0; rw < 64; ++rw) {
            int row = (wid << 6) | rw;
            int rs = __builtin_amdgcn_readfirstlane(rex[row]);
            int rc = __builtin_amdgcn_readfirstlane(rcnt[row]);
            if (rc <= 1) {
                if (rc == 1 && lane == 0) ecsr[s + rs] = dst[rs];
                continue;
            }
            if (rc <= 64) {
                int key = 0x7FFFFFFF, val = 0;
                if (lane < rc) { int2 q = dst[rs + lane]; key = q.x; val = q.y; }
                #pragma unroll
                for (int k = 2; k <= 64; k <<= 1) {
                    #pragma unroll
                    for (int j = k >> 1; j > 0; j >>= 1) {
                        int ok = __shfl_xor(key, j, 64);
                        int ov = __shfl_xor(val, j, 64);
                        bool lower = (lane & j) == 0;
                        bool asc   = (lane & k) == 0;   // k=64: ascending everywhere
                        bool keepSmaller = (asc == lower);
                        bool take = keepSmaller ? (ok < key) : (ok > key);
                        if (take) { key = ok; val = ov; }
                    }
                }
                if (lane < rc) ecsr[s + rs + lane] = make_int2(key, val);
            } else {
                // degenerate long row (statistically never): lane-0 insertion in LDS
                if (lane == 0) {
                    for (int i = rs + 1; i < rs + rc; ++i) {
                        int2 kk = dst[i];
                        int j = i - 1;
                        while (j >= rs && dst[j].x > kk.x) { dst[j + 1] = dst[j]; --j; }
                        dst[j + 1] = kk;
                    }
                }
                for (int i = lane; i < rc; i += 64) ecsr[s + rs + i] = dst[rs + i];
            }
        }
    } else {
        // degenerate oversized bucket (statistically never): unsorted direct
        for (int i = s + t; i < e; i += 256) {
            int2 ed = ebuf[i];
            int pos = atomicAdd(&curs[(ed.x >> 18) & 255], 1);
            ecsr[s + pos] = make_int2(ed.x & 0x3FFFF, ed.y);
        }
    }
}

// ---------------- gather SpMM: one wave per row, lane = dim ----------------
// bf16 gather operand, fp32 math, packed int2 edges. LAYER 1: allb->y1b.
// LAYER 2: y1b->y2b. LAYER 3: y2b->out, fused out = 0.25*(e0+y1+y2+acc).
template <int LAYER>
__global__ __launch_bounds__(256) void k_spmm(const int* __restrict__ row_start,
                                              const int2* __restrict__ ecsr,
                                              const ushort16* __restrict__ x,
                                              ushort16* __restrict__ yb,
                                              const ushort16* __restrict__ y1b,
                                              const ushort16* __restrict__ y2b,
                                              const float* __restrict__ user,
                                              const float* __restrict__ item,
                                              float* __restrict__ out) {
    int gid = blockIdx.x * blockDim.x + threadIdx.x;
    int r = gid >> 6;
    int lane = threadIdx.x & 63;
    if (r >= N_NODES) return;
    int s = __builtin_amdgcn_readfirstlane(row_start[r]);
    int e = __builtin_amdgcn_readfirstlane(row_start[r + 1]);
    float acc = 0.f;
    int i = s;
    for (; i + 8 <= e; i += 8) {
        int2 e0 = ecsr[i],   e1 = ecsr[i+1], e2 = ecsr[i+2], e3 = ecsr[i+3];
        int2 e4 = ecsr[i+4], e5 = ecsr[i+5], e6 = ecsr[i+6], e7 = ecsr[i+7];
        float x0 = b2f(x[(size_t)e0.x * 64 + lane]);
        float x1 = b2f(x[(size_t)e1.x * 64 + lane]);
        float x2 = b2f(x[(size_t)e2.x * 64 + lane]);
        float x3 = b2f(x[(size_t)e3.x * 64 + lane]);
        float x4 = b2f(x[(size_t)e4.x * 64 + lane]);
        float x5 = b2f(x[(size_t)e5.x * 64 + lane]);
        float x6 = b2f(x[(size_t)e6.x * 64 + lane]);
        float x7 = b2f(x[(size_t)e7.x * 64 + lane]);
        acc += __int_as_float(e0.y) * x0; acc += __int_as_float(e1.y) * x1;
        acc += __int_as_float(e2.y) * x2; acc += __int_as_float(e3.y) * x3;
        acc += __int_as_float(e4.y) * x4; acc += __int_as_float(e5.y) * x5;
        acc += __int_as_float(e6.y) * x6; acc += __int_as_float(e7.y) * x7;
    }
    for (; i + 4 <= e; i += 4) {
        int2 e0 = ecsr[i], e1 = ecsr[i+1], e2 = ecsr[i+2], e3 = ecsr[i+3];
        float x0 = b2f(x[(size_t)e0.x * 64 + lane]);
        float x1 = b2f(x[(size_t)e1.x * 64 + lane]);
        float x2 = b2f(x[(size_t)e2.x * 64 + lane]);
        float x3 = b2f(x[(size_t)e3.x * 64 + lane]);
        acc += __int_as_float(e0.y) * x0; acc += __int_as_float(e1.y) * x1;
        acc += __int_as_float(e2.y) * x2; acc += __int_as_float(e3.y) * x3;
    }
    for (; i < e; ++i) {
        int2 ed = ecsr[i];
        acc += __int_as_float(ed.y) * b2f(x[(size_t)ed.x * 64 + lane]);
    }

    size_t o = (size_t)r * 64 + lane;
    if constexpr (LAYER == 3) {
        float e0v = (r < N_USERS) ? user[o] : item[o - (size_t)N_USERS * 64];
        out[o] = 0.25f * (e0v + b2f(y1b[o]) + b2f(y2b[o]) + acc);
    } else {
        yb[o] = f2b(acc);
    }
}

// ---------------- fallback path (ws too small): atomic scatter SpMM ----------------
__global__ __launch_bounds__(256) void k_init(const float* __restrict__ user,
                                              const float* __restrict__ item,
                                              float* __restrict__ cur,
                                              float* __restrict__ out) {
    int i = blockIdx.x * blockDim.x + threadIdx.x;
    const int total4 = N_NODES * 16;
    if (i >= total4) return;
    const int user4 = N_USERS * 16;
    float4 v = (i < user4) ? ((const float4*)user)[i]
                           : ((const float4*)item)[i - user4];
    ((float4*)cur)[i] = v;
    ((float4*)out)[i] = make_float4(0.25f * v.x, 0.25f * v.y,
                                    0.25f * v.z, 0.25f * v.w);
}

__global__ __launch_bounds__(256) void k_edge_atomic(const int* __restrict__ rows,
                                                     const int* __restrict__ cols,
                                                     const float* __restrict__ vals,
                                                     const float* __restrict__ x,
                                                     float* __restrict__ y) {
    long long gid = (long long)blockIdx.x * blockDim.x + threadIdx.x;
    int e = (int)(gid >> 6);
    int lane = threadIdx.x & 63;
    if (e >= N_EDGES) return;
    int r = rows[e], c = cols[e];
    float v = vals[e];
    atomicAdd(&y[r * 64 + lane], v * x[c * 64 + lane]);
}

__global__ __launch_bounds__(256) void k_accum(const float* __restrict__ y,
                                               float* __restrict__ out) {
    int i = blockIdx.x * blockDim.x + threadIdx.x;
    const int total4 = N_NODES * 16;
    if (i >= total4) return;
    float4 a = ((const float4*)y)[i];
    float4 o = ((float4*)out)[i];
    o.x += 0.25f * a.x; o.y += 0.25f * a.y;
    o.z += 0.25f * a.z; o.w += 0.25f * a.w;
    ((float4*)out)[i] = o;
}

extern "C" void kernel_launch(void* const* d_in, const int* in_sizes, int n_in,
                              void* d_out, int out_size, void* d_ws, size_t ws_size,
                              hipStream_t stream) {
    const float* user = (const float*)d_in[0];
    const float* item = (const float*)d_in[1];
    const int*   rows = (const int*)d_in[2];
    const int*   cols = (const int*)d_in[3];
    const float* vals = (const float*)d_in[4];
    float* out = (float*)d_out;

    const int CVT_BLOCKS  = (N_NODES * 16 + 255) / 256;        // 9375
    const int SPMM_BLOCKS = (N_NODES * 64 + 255) / 256;        // 37500

    auto align256 = [](size_t x) { return (x + 255) & ~(size_t)255; };
    const size_t sz_embf = align256((size_t)N_NODES * 64 * sizeof(float));  // 38.4 MB
    const size_t sz_embb = align256((size_t)N_NODES * 64 * sizeof(short));  // 19.2 MB
    const size_t sz_ecsr = align256((size_t)N_EDGES * sizeof(int2));        // 24 MB
    const size_t sz_rs   = align256((size_t)(N_NODES + 1) * sizeof(int));
    const size_t sz_bk   = align256((size_t)(NBKT + 1) * sizeof(int));
    const size_t need_csr = 3 * sz_embb + sz_ecsr + sz_rs + 3 * sz_bk;      // ~82.5 MB

    char* p = (char*)d_ws;
    if (ws_size >= need_csr) {
        ushort16* allb = (ushort16*)p; p += sz_embb;
        ushort16* y1b  = (ushort16*)p; p += sz_embb;   // ebuf (24 MB) aliases y1b+y2b
        ushort16* y2b  = (ushort16*)p; p += sz_embb;
        int2*  ecsr      = (int2*)p;  p += sz_ecsr;
        int*   row_start = (int*)p;   p += sz_rs;
        int*   bucket_cnt    = (int*)p; p += sz_bk;
        int*   bucket_start  = (int*)p; p += sz_bk;
        int*   bucket_cursor = (int*)p; p += sz_bk;
        int2*  ebuf = (int2*)y1b;      // dead before y1b is written

        hipMemsetAsync(bucket_cnt, 0, (size_t)NBKT * sizeof(int), stream);
        k_cvt<<<CVT_BLOCKS, 256, 0, stream>>>(user, item, allb);
        k_bucket_count<<<ABLK, 256, 0, stream>>>(rows, bucket_cnt);
        k_bucket_scan<<<1, 1024, 0, stream>>>(bucket_cnt, bucket_start, bucket_cursor, row_start);
        k_bucket_scatter<<<ABLK, 256, 0, stream>>>(rows, cols, vals, bucket_cursor, ebuf);
        k_sort_bucket<<<NBKT, 256, 0, stream>>>(ebuf, bucket_start, row_start, ecsr);

        k_spmm<1><<<SPMM_BLOCKS, 256, 0, stream>>>(row_start, ecsr, allb,
                                                   y1b, nullptr, nullptr, user, item, out);
        k_spmm<2><<<SPMM_BLOCKS, 256, 0, stream>>>(row_start, ecsr, y1b,
                                                   y2b, nullptr, nullptr, user, item, out);
        k_spmm<3><<<SPMM_BLOCKS, 256, 0, stream>>>(row_start, ecsr, y2b,
                                                   nullptr, y1b, y2b, user, item, out);
    } else {
        // fallback: atomic scatter SpMM (fp32), needs only 2 embedding buffers
        float* bufA = (float*)p; p += sz_embf;
        float* bufB = (float*)p; p += sz_embf;
        float* in   = bufA;
        float* y    = bufB;
        const long long EA_THREADS = (long long)N_EDGES * 64;
        const int EA_BLOCKS = (int)((EA_THREADS + 255) / 256);

        k_init<<<CVT_BLOCKS, 256, 0, stream>>>(user, item, in, out);
        for (int l = 0; l < 3; ++l) {
            hipMemsetAsync(y, 0, (size_t)N_NODES * 64 * sizeof(float), stream);
            k_edge_atomic<<<EA_BLOCKS, 256, 0, stream>>>(rows, cols, vals, in, y);
            k_accum<<<CVT_BLOCKS, 256, 0, stream>>>(y, out);
            float* t = in; in = y; y = t;
        }
    }
}

// Round 8
// 349.548 us; speedup vs baseline: 2.2848x; 1.2397x over previous
//
#include <hip/hip_runtime.h>
#include <cstddef>
#include <cstdint>

#define N_USERS 100000
#define N_ITEMS 50000
#define N_NODES 150000
#define N_EDGES 3000000
// EMBED_DIM = 64 == wavefront size: lane d owns dim d of a row.

#define NBKT 586          // ceil(150000 / 256) buckets of 256 rows
#define BCHUNK 4096       // edges per multisplit block
#define ABLK ((N_EDGES + BCHUNK - 1) / BCHUNK)   // 733
#define NCLS 16           // coarse column classes (col >> 14), band ~2MB bf16

typedef unsigned int uint32;
typedef unsigned short ushort16;

// fp32 -> bf16 with round-to-nearest-even
__device__ __forceinline__ ushort16 f2b(float f) {
    uint32 b = __float_as_uint(f);
    b += 0x7FFFu + ((b >> 16) & 1u);
    return (ushort16)(b >> 16);
}
__device__ __forceinline__ float b2f(ushort16 h) {
    return __uint_as_float(((uint32)h) << 16);
}

// ---------------- convert concat(user,item) -> bf16 allb ----------------
__global__ __launch_bounds__(256) void k_cvt(const float* __restrict__ user,
                                             const float* __restrict__ item,
                                             ushort16* __restrict__ allb) {
    int i = blockIdx.x * blockDim.x + threadIdx.x;          // float4 index
    const int total4 = N_NODES * 16;                        // 2,400,000
    if (i >= total4) return;
    const int user4 = N_USERS * 16;
    float4 v = (i < user4) ? ((const float4*)user)[i]
                           : ((const float4*)item)[i - user4];
    ushort4 h;
    h.x = f2b(v.x); h.y = f2b(v.y); h.z = f2b(v.z); h.w = f2b(v.w);
    ((ushort4*)allb)[i] = h;
}

// ---------------- phase A: bucket counts (LDS hist -> 586 global adds/block) ----
__global__ __launch_bounds__(256) void k_bucket_count(const int* __restrict__ rows,
                                                      int* __restrict__ bucket_cnt) {
    __shared__ int hist[NBKT];
    int t = threadIdx.x;
    for (int j = t; j < NBKT; j += 256) hist[j] = 0;
    __syncthreads();
    int s0 = blockIdx.x * BCHUNK;
    int e0 = min(s0 + BCHUNK, N_EDGES);
    for (int i = s0 + t; i < e0; i += 256)
        atomicAdd(&hist[rows[i] >> 8], 1);
    __syncthreads();
    for (int j = t; j < NBKT; j += 256)
        if (hist[j]) atomicAdd(&bucket_cnt[j], hist[j]);
}

// ---------------- tiny scan of 586 bucket counts ----------------
__global__ __launch_bounds__(1024) void k_bucket_scan(const int* __restrict__ bucket_cnt,
                                                      int* __restrict__ bucket_start,
                                                      int* __restrict__ bucket_cursor,
                                                      int* __restrict__ row_start) {
    __shared__ int sh[1024];
    int t = threadIdx.x;
    sh[t] = (t < NBKT) ? bucket_cnt[t] : 0;
    __syncthreads();
    for (int off = 1; off < 1024; off <<= 1) {
        int add = (t >= off) ? sh[t - off] : 0;
        __syncthreads();
        sh[t] += add;
        __syncthreads();
    }
    if (t < NBKT) {
        int st = (t == 0) ? 0 : sh[t - 1];
        bucket_start[t] = st;
        bucket_cursor[t] = st;
    }
    if (t == 0) { bucket_start[NBKT] = N_EDGES; row_start[N_NODES] = N_EDGES; }
}

// ---------------- phase B: bucket scatter (block-local runs -> full lines) ------
// packs (col 18b | row_lo 8b << 18, val) into int2
__global__ __launch_bounds__(256) void k_bucket_scatter(const int* __restrict__ rows,
                                                        const int* __restrict__ cols,
                                                        const float* __restrict__ vals,
                                                        int* __restrict__ bucket_cursor,
                                                        int2* __restrict__ ebuf) {
    __shared__ int hist[NBKT];
    __shared__ int base[NBKT];
    int t = threadIdx.x;
    for (int j = t; j < NBKT; j += 256) hist[j] = 0;
    __syncthreads();
    int s0 = blockIdx.x * BCHUNK;
    int e0 = min(s0 + BCHUNK, N_EDGES);
    for (int i = s0 + t; i < e0; i += 256)
        atomicAdd(&hist[rows[i] >> 8], 1);
    __syncthreads();
    for (int j = t; j < NBKT; j += 256) {
        int c = hist[j];
        base[j] = c ? atomicAdd(&bucket_cursor[j], c) : 0;
    }
    for (int j = t; j < NBKT; j += 256) hist[j] = 0;
    __syncthreads();
    for (int i = s0 + t; i < e0; i += 256) {
        int r = rows[i];
        int b = r >> 8;
        int off = atomicAdd(&hist[b], 1);
        ebuf[base[b] + off] = make_int2(cols[i] | ((r & 255) << 18),
                                        __float_as_int(vals[i]));
    }
}

// ---------------- phase C: per-bucket LDS COUNTING SORT on (row_lo, col>>14) ---
// Histogram 4096 keys -> in-LDS scan -> scatter straight to global ecsr
// (writes stay inside the bucket's private 40KB window -> single-XCD L2).
// Gives CSR row grouping + coarse column order, no bitonic, no dst staging.
__global__ __launch_bounds__(256) void k_csr_build(const int2* __restrict__ ebuf,
                                                   const int* __restrict__ bucket_start,
                                                   int* __restrict__ row_start,
                                                   int2* __restrict__ ecsr) {
    __shared__ int cnt2[256 * NCLS];   // key = (row_lo << 4) | colcls
    __shared__ int psum[256];
    int b = blockIdx.x, t = threadIdx.x;
    int rbase = b << 8;
    for (int j = t; j < 256 * NCLS; j += 256) cnt2[j] = 0;
    __syncthreads();
    int s = bucket_start[b], e = bucket_start[b + 1];
    for (int i = s + t; i < e; i += 256) {
        int2 ed = ebuf[i];
        int col = ed.x & 0x3FFFF;
        int key = (((ed.x >> 18) & 255) << 4) | (col >> 14);
        atomicAdd(&cnt2[key], 1);
    }
    __syncthreads();
    // exclusive scan of 4096 counters: thread t owns keys [t*16, t*16+16)
    int base = t * NCLS;
    int vals[NCLS];
    int local = 0;
    #pragma unroll
    for (int j = 0; j < NCLS; ++j) { vals[j] = cnt2[base + j]; local += vals[j]; }
    psum[t] = local;
    __syncthreads();
    for (int off = 1; off < 256; off <<= 1) {
        int add = (t >= off) ? psum[t - off] : 0;
        __syncthreads();
        psum[t] += add;
        __syncthreads();
    }
    int run = (t == 0) ? 0 : psum[t - 1];
    int rr = rbase + t;
    if (rr < N_NODES) row_start[rr] = s + run;   // row start = prefix at (t,cls=0)
    #pragma unroll
    for (int j = 0; j < NCLS; ++j) { int c = vals[j]; cnt2[base + j] = run; run += c; }
    __syncthreads();
    for (int i = s + t; i < e; i += 256) {
        int2 ed = ebuf[i];
        int col = ed.x & 0x3FFFF;
        int key = (((ed.x >> 18) & 255) << 4) | (col >> 14);
        int pos = atomicAdd(&cnt2[key], 1);
        ecsr[s + pos] = make_int2(col, ed.y);
    }
}

// ---------------- gather SpMM: one wave per row, lane = dim ----------------
// bf16 gather operand, fp32 math, packed int2 edges. LAYER 1: allb->y1b.
// LAYER 2: y1b->y2b. LAYER 3: y2b->out, fused out = 0.25*(e0+y1+y2+acc).
template <int LAYER>
__global__ __launch_bounds__(256) void k_spmm(const int* __restrict__ row_start,
                                              const int2* __restrict__ ecsr,
                                              const ushort16* __restrict__ x,
                                              ushort16* __restrict__ yb,
                                              const ushort16* __restrict__ y1b,
                                              const ushort16* __restrict__ y2b,
                                              const float* __restrict__ user,
                                              const float* __restrict__ item,
                                              float* __restrict__ out) {
    int gid = blockIdx.x * blockDim.x + threadIdx.x;
    int r = gid >> 6;
    int lane = threadIdx.x & 63;
    if (r >= N_NODES) return;
    int s = __builtin_amdgcn_readfirstlane(row_start[r]);
    int e = __builtin_amdgcn_readfirstlane(row_start[r + 1]);
    float acc = 0.f;
    int i = s;
    for (; i + 8 <= e; i += 8) {
        int2 e0 = ecsr[i],   e1 = ecsr[i+1], e2 = ecsr[i+2], e3 = ecsr[i+3];
        int2 e4 = ecsr[i+4], e5 = ecsr[i+5], e6 = ecsr[i+6], e7 = ecsr[i+7];
        float x0 = b2f(x[(size_t)e0.x * 64 + lane]);
        float x1 = b2f(x[(size_t)e1.x * 64 + lane]);
        float x2 = b2f(x[(size_t)e2.x * 64 + lane]);
        float x3 = b2f(x[(size_t)e3.x * 64 + lane]);
        float x4 = b2f(x[(size_t)e4.x * 64 + lane]);
        float x5 = b2f(x[(size_t)e5.x * 64 + lane]);
        float x6 = b2f(x[(size_t)e6.x * 64 + lane]);
        float x7 = b2f(x[(size_t)e7.x * 64 + lane]);
        acc += __int_as_float(e0.y) * x0; acc += __int_as_float(e1.y) * x1;
        acc += __int_as_float(e2.y) * x2; acc += __int_as_float(e3.y) * x3;
        acc += __int_as_float(e4.y) * x4; acc += __int_as_float(e5.y) * x5;
        acc += __int_as_float(e6.y) * x6; acc += __int_as_float(e7.y) * x7;
    }
    for (; i + 4 <= e; i += 4) {
        int2 e0 = ecsr[i], e1 = ecsr[i+1], e2 = ecsr[i+2], e3 = ecsr[i+3];
        float x0 = b2f(x[(size_t)e0.x * 64 + lane]);
        float x1 = b2f(x[(size_t)e1.x * 64 + lane]);
        float x2 = b2f(x[(size_t)e2.x * 64 + lane]);
        float x3 = b2f(x[(size_t)e3.x * 64 + lane]);
        acc += __int_as_float(e0.y) * x0; acc += __int_as_float(e1.y) * x1;
        acc += __int_as_float(e2.y) * x2; acc += __int_as_float(e3.y) * x3;
    }
    for (; i < e; ++i) {
        int2 ed = ecsr[i];
        acc += __int_as_float(ed.y) * b2f(x[(size_t)ed.x * 64 + lane]);
    }

    size_t o = (size_t)r * 64 + lane;
    if constexpr (LAYER == 3) {
        float e0v = (r < N_USERS) ? user[o] : item[o - (size_t)N_USERS * 64];
        out[o] = 0.25f * (e0v + b2f(y1b[o]) + b2f(y2b[o]) + acc);
    } else {
        yb[o] = f2b(acc);
    }
}

// ---------------- fallback path (ws too small): atomic scatter SpMM ----------------
__global__ __launch_bounds__(256) void k_init(const float* __restrict__ user,
                                              const float* __restrict__ item,
                                              float* __restrict__ cur,
                                              float* __restrict__ out) {
    int i = blockIdx.x * blockDim.x + threadIdx.x;
    const int total4 = N_NODES * 16;
    if (i >= total4) return;
    const int user4 = N_USERS * 16;
    float4 v = (i < user4) ? ((const float4*)user)[i]
                           : ((const float4*)item)[i - user4];
    ((float4*)cur)[i] = v;
    ((float4*)out)[i] = make_float4(0.25f * v.x, 0.25f * v.y,
                                    0.25f * v.z, 0.25f * v.w);
}

__global__ __launch_bounds__(256) void k_edge_atomic(const int* __restrict__ rows,
                                                     const int* __restrict__ cols,
                                                     const float* __restrict__ vals,
                                                     const float* __restrict__ x,
                                                     float* __restrict__ y) {
    long long gid = (long long)blockIdx.x * blockDim.x + threadIdx.x;
    int e = (int)(gid >> 6);
    int lane = threadIdx.x & 63;
    if (e >= N_EDGES) return;
    int r = rows[e], c = cols[e];
    float v = vals[e];
    atomicAdd(&y[r * 64 + lane], v * x[c * 64 + lane]);
}

__global__ __launch_bounds__(256) void k_accum(const float* __restrict__ y,
                                               float* __restrict__ out) {
    int i = blockIdx.x * blockDim.x + threadIdx.x;
    const int total4 = N_NODES * 16;
    if (i >= total4) return;
    float4 a = ((const float4*)y)[i];
    float4 o = ((float4*)out)[i];
    o.x += 0.25f * a.x; o.y += 0.25f * a.y;
    o.z += 0.25f * a.z; o.w += 0.25f * a.w;
    ((float4*)out)[i] = o;
}

extern "C" void kernel_launch(void* const* d_in, const int* in_sizes, int n_in,
                              void* d_out, int out_size, void* d_ws, size_t ws_size,
                              hipStream_t stream) {
    const float* user = (const float*)d_in[0];
    const float* item = (const float*)d_in[1];
    const int*   rows = (const int*)d_in[2];
    const int*   cols = (const int*)d_in[3];
    const float* vals = (const float*)d_in[4];
    float* out = (float*)d_out;

    const int CVT_BLOCKS  = (N_NODES * 16 + 255) / 256;        // 9375
    const int SPMM_BLOCKS = (N_NODES * 64 + 255) / 256;        // 37500

    auto align256 = [](size_t x) { return (x + 255) & ~(size_t)255; };
    const size_t sz_embf = align256((size_t)N_NODES * 64 * sizeof(float));  // 38.4 MB
    const size_t sz_embb = align256((size_t)N_NODES * 64 * sizeof(short));  // 19.2 MB
    const size_t sz_ecsr = align256((size_t)N_EDGES * sizeof(int2));        // 24 MB
    const size_t sz_rs   = align256((size_t)(N_NODES + 1) * sizeof(int));
    const size_t sz_bk   = align256((size_t)(NBKT + 1) * sizeof(int));
    const size_t need_csr = 3 * sz_embb + sz_ecsr + sz_rs + 3 * sz_bk;      // ~82.5 MB

    char* p = (char*)d_ws;
    if (ws_size >= need_csr) {
        ushort16* allb = (ushort16*)p; p += sz_embb;
        ushort16* y1b  = (ushort16*)p; p += sz_embb;   // ebuf (24 MB) aliases y1b+y2b
        ushort16* y2b  = (ushort16*)p; p += sz_embb;
        int2*  ecsr      = (int2*)p;  p += sz_ecsr;
        int*   row_start = (int*)p;   p += sz_rs;
        int*   bucket_cnt    = (int*)p; p += sz_bk;
        int*   bucket_start  = (int*)p; p += sz_bk;
        int*   bucket_cursor = (int*)p; p += sz_bk;
        int2*  ebuf = (int2*)y1b;      // dead before y1b is written

        hipMemsetAsync(bucket_cnt, 0, (size_t)NBKT * sizeof(int), stream);
        k_cvt<<<CVT_BLOCKS, 256, 0, stream>>>(user, item, allb);
        k_bucket_count<<<ABLK, 256, 0, stream>>>(rows, bucket_cnt);
        k_bucket_scan<<<1, 1024, 0, stream>>>(bucket_cnt, bucket_start, bucket_cursor, row_start);
        k_bucket_scatter<<<ABLK, 256, 0, stream>>>(rows, cols, vals, bucket_cursor, ebuf);
        k_csr_build<<<NBKT, 256, 0, stream>>>(ebuf, bucket_start, row_start, ecsr);

        k_spmm<1><<<SPMM_BLOCKS, 256, 0, stream>>>(row_start, ecsr, allb,
                                                   y1b, nullptr, nullptr, user, item, out);
        k_spmm<2><<<SPMM_BLOCKS, 256, 0, stream>>>(row_start, ecsr, y1b,
                                                   y2b, nullptr, nullptr, user, item, out);
        k_spmm<3><<<SPMM_BLOCKS, 256, 0, stream>>>(row_start, ecsr, y2b,
                                                   nullptr, y1b, y2b, user, item, out);
    } else {
        // fallback: atomic scatter SpMM (fp32), needs only 2 embedding buffers
        float* bufA = (float*)p; p += sz_embf;
        float* bufB = (float*)p; p += sz_embf;
        float* in   = bufA;
        float* y    = bufB;
        const long long EA_THREADS = (long long)N_EDGES * 64;
        const int EA_BLOCKS = (int)((EA_THREADS + 255) / 256);

        k_init<<<CVT_BLOCKS, 256, 0, stream>>>(user, item, in, out);
        for (int l = 0; l < 3; ++l) {
            hipMemsetAsync(y, 0, (size_t)N_NODES * 64 * sizeof(float), stream);
            k_edge_atomic<<<EA_BLOCKS, 256, 0, stream>>>(rows, cols, vals, in, y);
            k_accum<<<CVT_BLOCKS, 256, 0, stream>>>(y, out);
            float* t = in; in = y; y = t;
        }
    }
}